// Round 12
// baseline (305.125 us; speedup 1.0000x reference)
//

#include <hip/hip_runtime.h>

// R29b: resubmit of R29 (second infra "container failed twice"; audit clean
// — uniform barriers, correct builtin signature V2iiiIbIb, self-correcting
// wave-uniform semantic probe, shfl fallback; R24 precedent: same failure
// signature, resubmit ran fine).
// R29 = R28 (verified 237.1us, absmax 0.0039) with the fan's 8 ds_bpermute
// + 8 cndmask replaced by 8 v_permlane32_swap (VALU-only lane<->lane+32
// exchange, no LDS pipe, no lgkm). R28 post-mortem: VALUBusy 45.7->52.7 at
// zero wall change -> step sits where chain latency ~ per-SIMD issue; the
// last identified on-chain slack is the bpermute fan (~100cy LDS latency,
// entangled with the barrier's lgkmcnt(0)). Fan OUTPUT values are
// bit-identical to R28 -> absmax 0.00390625 expected exactly.

typedef unsigned short u16;
typedef unsigned int   u32;
typedef float f32x4 __attribute__((ext_vector_type(4)));
typedef short s16x8 __attribute__((ext_vector_type(8)));
typedef int   i32x2 __attribute__((ext_vector_type(2)));

// LDS-only workgroup barrier: waits local ops, does NOT drain vmcnt.
#define WGBAR() asm volatile("s_waitcnt lgkmcnt(0)\n\ts_barrier" ::: "memory")

#if defined(__has_builtin)
#if __has_builtin(__builtin_amdgcn_permlane32_swap)
#define HAVE_PLSWAP 1
#endif
#endif

__device__ __forceinline__ float bf2f(u16 u){
  union { u32 i; float f; } v; v.i = ((u32)u) << 16; return v.f;
}
__device__ __forceinline__ u16 f2bf(float f){
  union { float fl; u32 i; } v; v.fl = f;
  u32 r = v.i + 0x7fffu + ((v.i >> 16) & 1u);   // RNE
  return (u16)(r >> 16);
}
__device__ __forceinline__ float frcp(float x){ return __builtin_amdgcn_rcpf(x); }
__device__ __forceinline__ float sigm_f(float x){          // fast sigmoid
  float e = __expf(-x);
  return frcp(1.f + e);
}
__device__ __forceinline__ float tanh_f(float x){          // fast tanh, clamped
  x = fminf(fmaxf(x, -15.f), 15.f);
  float e = __expf(-2.f * x);
  return (1.f - e) * frcp(1.f + e);
}
__device__ __forceinline__ f32x4 mf(s16x8 a, s16x8 b, f32x4 c){
  return __builtin_amdgcn_mfma_f32_16x16x32_bf16(a, b, c, 0, 0, 0);
}
__device__ __forceinline__ float ldf(const void* p, int i, bool f32in){
  if (f32in) return ((const float*)p)[i];
  return bf2f(((const u16*)p)[i]);
}

#define TPB 256
#define RPB 4      // batch rows per block -> 512 blocks, 2 blocks/CU

extern "C" __global__ __launch_bounds__(TPB, 2) void LSTM_Seq2Dis_15272903704706_kernel(
    const int* idx, const void* emb, const void* Wk, const void* Uk,
    const void* bias, const void* W1, const void* b1,
    const void* W2, const void* b2, float* out)
{
  __shared__ __align__(16) u16 ering[16][1024];   // e frags per chunk step (32 KB)
  __shared__ __align__(16) u16 hbuf[4][2][512];   // chunk h: dense head + A-frags (8 KB)
  __shared__ __align__(16) u16 dwork[4][2][512];  // per-wave d1 scratch (8 KB)
  __shared__ int   tokl[1024];                    // token ids [s][r], r 0..3 (4 KB)
  __shared__ int   s_f32;

  const int tid = threadIdx.x;
  const int wv  = tid >> 6, ln = tid & 63;
  const int r0  = blockIdx.x * RPB;

  if (tid == 0){
    const u32* ew = (const u32*)emb;
    int hits = 0;
    for (int i = 0; i < 64; i++){
      u32 ef = (ew[i] >> 7) & 0xFFu;
      if (ef >= 112u && ef <= 127u) hits++;
    }
    s_f32 = (hits < 32) ? 1 : 0;
  }

  for (int i = tid; i < 16*1024; i += TPB) ((u16*)ering)[i] = 0;
  for (int i = tid; i < 4*2*512; i += TPB) ((u16*)hbuf)[i]  = 0;
  for (int i = tid; i < 1024;    i += TPB){
    int r = i & 3, s = i >> 2;
    tokl[i] = idx[(r0 + r)*256 + s];
  }
  __syncthreads();
  const bool f32in = (s_f32 != 0);

  // ---- z-GEMM B-frags, GATE-MAJOR cols (R22/R23-verified): lane owns unit
  // jown = wv*16 + (ln&15); tile t = gate t, B col = t*50 + jown.
  const int jown = wv*16 + (ln & 15);
  const bool jval = (jown < 50);
  s16x8 bz[4][4];
  #pragma unroll
  for (int t = 0; t < 4; t++){
    const int col = t*50 + jown;
    #pragma unroll
    for (int kt = 0; kt < 4; kt++){
      s16x8 v;
      #pragma unroll
      for (int j = 0; j < 8; j++){
        int k = kt*32 + ((ln >> 4) << 3) + j;
        float w = 0.f;
        if (jval){
          if (k < 50)                  w = ldf(Uk, k*200 + col, f32in);
          else if (k >= 64 && k < 114) w = ldf(Wk, (k-64)*200 + col, f32in);
        }
        v[j] = (short)f2bf(w);
      }
      bz[t][kt] = v;
    }
  }
  f32x4 bgv[4];                                   // bias splat (C-init for ae)
  #pragma unroll
  for (int t = 0; t < 4; t++){
    float b = jval ? ldf(bias, t*50 + jown, f32in) : 0.f;
    bgv[t] = (f32x4){b, b, b, b};
  }

  // ---- dense W1 fragments + b1/W2 ----
  s16x8 w1f[4][2];
  float b1v[4], w2v[4];
  #pragma unroll
  for (int nt = 0; nt < 4; nt++){
    int c = nt*16 + (ln & 15);
    b1v[nt] = (c < 50) ? ldf(b1, c, f32in) : 0.f;
    w2v[nt] = (c < 50) ? ldf(W2, c, f32in) : 0.f;
    #pragma unroll
    for (int kt = 0; kt < 2; kt++){
      s16x8 v;
      #pragma unroll
      for (int j = 0; j < 8; j++){
        int k = kt*32 + ((ln >> 4) << 3) + j;
        v[j] = (short)((k < 50 && c < 50) ? f2bf(ldf(W1, k*50 + c, f32in)) : (u16)0);
      }
      w1f[nt][kt] = v;
    }
  }
  const float b2s = ldf(b2, 0, f32in);

  const int gr = tid / 50, gj = tid - gr*50;      // gather threads 0..199, gr 0..3
  const int foff = (gj >> 5)*512 + (gr + (((gj & 31) >> 3) << 4))*8 + (gj & 7);

  // ---- gate spread (R28): ONE fan stage, 2 cells/lane.
  const int q  = ln >> 4;
  const int hi = q >> 1;
  const bool wrt = jval && ((q & 1) == 0);        // one writer per (rowpair,unit)
  float creg[2] = {0.f, 0.f};                     // cell state rows hi*2+{0,1}
  const int eo16 = ((jown & 31) >> 3) << 4;

#ifdef HAVE_PLSWAP
  // ---- one-time semantic probe for v_permlane32_swap operand convention.
  // Real-HW reading (newA.hi <- B.lo / newB.lo <- A.hi): probe gives
  // semA=false -> branch B: z = swap(own, partner).x.
  // Reversed reading (newA.lo <- B.hi): semA=true -> branch A:
  // z = swap(partner, own).y. Both branches produce identical fan output.
  bool semA;
  {
    i32x2 pr = __builtin_amdgcn_permlane32_swap((int)ln, 4096 + (int)ln, false, false);
    semA = (bool)__any(hi && (pr.y == (int)(ln - 32)));
  }
#endif

  auto dense_head = [&](int tcd){
    const int mt = wv;                             // 64 m-rows -> 1 tile/wave
    s16x8 a0 = *(const s16x8*)&hbuf[mt][0][ln*8];
    s16x8 a1 = *(const s16x8*)&hbuf[mt][1][ln*8];
    #pragma unroll
    for (int nt = 0; nt < 4; nt++){                // d1 = relu(h@W1+b1)
      f32x4 acc = {0.f,0.f,0.f,0.f};
      acc = mf(a0, w1f[nt][0], acc);
      acc = mf(a1, w1f[nt][1], acc);
      int c = nt*16 + (ln & 15);
      #pragma unroll
      for (int r = 0; r < 4; r++){
        float v = fmaxf(acc[r] + b1v[nt], 0.f);
        int row16 = ((ln >> 4) << 2) + r;
        dwork[wv][c >> 5][(row16 + (((c & 31) >> 3) << 4))*8 + (c & 7)] = f2bf(v);
      }
    }
    s16x8 d0 = *(const s16x8*)&dwork[wv][0][ln*8];
    s16x8 d1 = *(const s16x8*)&dwork[wv][1][ln*8];
    float part[4] = {0.f,0.f,0.f,0.f};
    #pragma unroll
    for (int nt = 0; nt < 4; nt++){                // d2 = relu(d1@W1+b1) . W2
      f32x4 acc = {0.f,0.f,0.f,0.f};
      acc = mf(d0, w1f[nt][0], acc);
      acc = mf(d1, w1f[nt][1], acc);
      #pragma unroll
      for (int r = 0; r < 4; r++)
        part[r] += fmaxf(acc[r] + b1v[nt], 0.f) * w2v[nt];
    }
    #pragma unroll
    for (int d = 1; d < 16; d <<= 1)
      #pragma unroll
      for (int r = 0; r < 4; r++) part[r] += __shfl_xor(part[r], d, 16);
    if ((ln & 15) == 0){
      int qq = ln >> 4;
      #pragma unroll
      for (int r = 0; r < 4; r++){
        int m = mt*16 + (qq << 2) + r;
        int sl4 = m >> 2, rb = m & 3;
        float z = part[r] + b2s;
        z = fmaxf(fminf(z, 1.0f), -1.0f);          // safety clamp
        out[(r0 + rb)*256 + tcd + sl4] = sigm_f(z);
      }
    }
  };

  // ---- prologue: issue chunk-0 gather loads into registers ----
  float ev[16];
  if (tid < 200){
    #pragma unroll
    for (int sl = 0; sl < 16; sl++)
      ev[sl] = ldf(emb, tokl[sl*4 + gr]*50 + gj, f32in);
  }

  for (int ch = 0; ch < 16; ch++){
    const int tc = ch*16;

    // ---- write ering from regs; issue next chunk's loads; head off-chain ----
    if (tid < 200){
      #pragma unroll
      for (int sl = 0; sl < 16; sl++)
        ering[sl][foff] = f2bf(ev[sl]);
      if (ch < 15){
        const int tn = tc + 16;
        #pragma unroll
        for (int sl = 0; sl < 16; sl++)
          ev[sl] = ldf(emb, tokl[(tn + sl)*4 + gr]*50 + gj, f32in);
      }
    }
    if (ch > 0) dense_head(tc - 16);    // prev chunk's head, off the chain
    WGBAR();                             // ering ready; hbuf consumed (LDS only)

    // ---- sl=0 e-part + bias, folded into C-init (split-K, off-chain) ----
    s16x8 e0 = *(const s16x8*)&ering[0][ln*8];
    s16x8 e1 = *(const s16x8*)&ering[0][512 + ln*8];
    f32x4 ae[4];
    #pragma unroll
    for (int t = 0; t < 4; t++){
      f32x4 a = bgv[t];
      a = mf(e1, bz[t][3], a);
      a = mf(e0, bz[t][2], a);
      ae[t] = a;
    }

    for (int sl = 0; sl < 16; sl++){
      // ---- A-frags straight from hbuf (h written at step sl-1) ----
      const int prev = (sl + 15) & 15;
      const int aoffr = ln*8 + (prev & 3)*32;
      s16x8 av0 = *(const s16x8*)&hbuf[prev >> 2][0][aoffr];
      s16x8 av1 = *(const s16x8*)&hbuf[prev >> 2][1][aoffr];
      f32x4 g4[4];
      #pragma unroll
      for (int t = 0; t < 4; t++){
        f32x4 a = ae[t];                 // C-init carries e-part + bias
        a = mf(av0, bz[t][0], a);
        a = mf(av1, bz[t][1], a);
        g4[t] = a;
      }

      // ---- ONE fan stage via permlane32_swap (VALU, no LDS pipe) ----
      // target: z0 lanes0-31 = own g4[0], lanes32-63 = partner g4[2]; z1 same for 1/3.
      float z0[4], z1[4];
#ifdef HAVE_PLSWAP
      if (semA){
        #pragma unroll
        for (int t = 0; t < 4; t++){
          i32x2 r0p = __builtin_amdgcn_permlane32_swap(
              __float_as_int(g4[t][2]), __float_as_int(g4[t][0]), false, false);
          i32x2 r1p = __builtin_amdgcn_permlane32_swap(
              __float_as_int(g4[t][3]), __float_as_int(g4[t][1]), false, false);
          z0[t] = __int_as_float(r0p.y);
          z1[t] = __int_as_float(r1p.y);
        }
      } else {
        #pragma unroll
        for (int t = 0; t < 4; t++){
          i32x2 r0p = __builtin_amdgcn_permlane32_swap(
              __float_as_int(g4[t][0]), __float_as_int(g4[t][2]), false, false);
          i32x2 r1p = __builtin_amdgcn_permlane32_swap(
              __float_as_int(g4[t][1]), __float_as_int(g4[t][3]), false, false);
          z0[t] = __int_as_float(r0p.x);
          z1[t] = __int_as_float(r1p.x);
        }
      }
#else
      #pragma unroll
      for (int t = 0; t < 4; t++){
        float s2 = __shfl_xor(g4[t][2], 32);
        float s3 = __shfl_xor(g4[t][3], 32);
        z0[t] = hi ? s2 : g4[t][0];
        z1[t] = hi ? s3 : g4[t][1];
      }
#endif

      // ---- gates in-register, 2 cells/lane (rows hi*2+{0,1}, unit jown) ----
      float iv0 = sigm_f(z0[0]), fv0 = sigm_f(z0[1]);
      float gv0 = tanh_f(z0[2]), ov0 = sigm_f(z0[3]);
      float iv1 = sigm_f(z1[0]), fv1 = sigm_f(z1[1]);
      float gv1 = tanh_f(z1[2]), ov1 = sigm_f(z1[3]);
      float c0 = fv0 * creg[0] + iv0 * gv0;  creg[0] = c0;
      float c1 = fv1 * creg[1] + iv1 * gv1;  creg[1] = c1;
      u16 hb0 = f2bf(ov0 * tanh_f(c0));
      u16 hb1 = f2bf(ov1 * tanh_f(c1));
      if (wrt){
        const int m0 = sl*4 + hi*2;            // row = hi*2 + rp
        hbuf[m0 >> 4][jown >> 5][((m0 & 15) + eo16)*8 + (jown & 7)] = hb0;
        const int m1 = m0 + 1;
        hbuf[m1 >> 4][jown >> 5][((m1 & 15) + eo16)*8 + (jown & 7)] = hb1;
      }

      // ---- pre-barrier: next step's e-frags + e-part MFMAs (off-chain) ----
      if (sl < 15){
        e0 = *(const s16x8*)&ering[sl + 1][ln*8];
        e1 = *(const s16x8*)&ering[sl + 1][512 + ln*8];
        #pragma unroll
        for (int t = 0; t < 4; t++){
          f32x4 a = bgv[t];
          a = mf(e1, bz[t][3], a);
          a = mf(e0, bz[t][2], a);
          ae[t] = a;
        }
      }
      WGBAR();           // h visible -> next step may read (LDS only)
    }
  }

  dense_head(240);                       // last chunk's head
}

extern "C" void kernel_launch(void* const* d_in, const int* in_sizes, int n_in,
                              void* d_out, int out_size, void* d_ws, size_t ws_size,
                              hipStream_t stream) {
  (void)in_sizes; (void)n_in; (void)out_size; (void)d_ws; (void)ws_size;
  hipLaunchKernelGGL(LSTM_Seq2Dis_15272903704706_kernel,
                     dim3(512), dim3(TPB), 0, stream,
                     (const int*)d_in[0], d_in[1], d_in[2], d_in[3], d_in[4],
                     d_in[5], d_in[6], d_in[7], d_in[8], (float*)d_out);
}

// Round 13
// 287.359 us; speedup vs baseline: 1.0618x; 1.0618x over previous
//

#include <hip/hip_runtime.h>

// R30 = exact revert to R28 (verified 237.1us best-dispatch, absmax 0.0039).
// R29b post-mortem: permlane32_swap fan = 253.8us (tied-operand movs +
// dual-result pressure > the bpermute latency it removed, which was hidden
// under the barrier anyway). Session floor analysis: issue (~1120cy VALU/
// SIMD/step @ 2 waves) and chain (~barrier+LDS turnaround + 6-deep trans)
// are simultaneously tight at ~2130cy/step; R23-R29 variants all land
// 237-246us or worse. This is the measured structural floor for the
// 256-step cross-wave serial recurrence.

typedef unsigned short u16;
typedef unsigned int   u32;
typedef float f32x4 __attribute__((ext_vector_type(4)));
typedef short s16x8 __attribute__((ext_vector_type(8)));

// LDS-only workgroup barrier: waits local ops, does NOT drain vmcnt.
#define WGBAR() asm volatile("s_waitcnt lgkmcnt(0)\n\ts_barrier" ::: "memory")

__device__ __forceinline__ float bf2f(u16 u){
  union { u32 i; float f; } v; v.i = ((u32)u) << 16; return v.f;
}
__device__ __forceinline__ u16 f2bf(float f){
  union { float fl; u32 i; } v; v.fl = f;
  u32 r = v.i + 0x7fffu + ((v.i >> 16) & 1u);   // RNE
  return (u16)(r >> 16);
}
__device__ __forceinline__ float frcp(float x){ return __builtin_amdgcn_rcpf(x); }
__device__ __forceinline__ float sigm_f(float x){          // fast sigmoid
  float e = __expf(-x);
  return frcp(1.f + e);
}
__device__ __forceinline__ float tanh_f(float x){          // fast tanh, clamped
  x = fminf(fmaxf(x, -15.f), 15.f);
  float e = __expf(-2.f * x);
  return (1.f - e) * frcp(1.f + e);
}
__device__ __forceinline__ f32x4 mf(s16x8 a, s16x8 b, f32x4 c){
  return __builtin_amdgcn_mfma_f32_16x16x32_bf16(a, b, c, 0, 0, 0);
}
__device__ __forceinline__ float ldf(const void* p, int i, bool f32in){
  if (f32in) return ((const float*)p)[i];
  return bf2f(((const u16*)p)[i]);
}

#define TPB 256
#define RPB 4      // batch rows per block -> 512 blocks, 2 blocks/CU

extern "C" __global__ __launch_bounds__(TPB, 2) void LSTM_Seq2Dis_15272903704706_kernel(
    const int* idx, const void* emb, const void* Wk, const void* Uk,
    const void* bias, const void* W1, const void* b1,
    const void* W2, const void* b2, float* out)
{
  __shared__ __align__(16) u16 ering[16][1024];   // e frags per chunk step (32 KB)
  __shared__ __align__(16) u16 hbuf[4][2][512];   // chunk h: dense head + A-frags (8 KB)
  __shared__ __align__(16) u16 dwork[4][2][512];  // per-wave d1 scratch (8 KB)
  __shared__ int   tokl[1024];                    // token ids [s][r], r 0..3 (4 KB)
  __shared__ int   s_f32;

  const int tid = threadIdx.x;
  const int wv  = tid >> 6, ln = tid & 63;
  const int r0  = blockIdx.x * RPB;

  if (tid == 0){
    const u32* ew = (const u32*)emb;
    int hits = 0;
    for (int i = 0; i < 64; i++){
      u32 ef = (ew[i] >> 7) & 0xFFu;
      if (ef >= 112u && ef <= 127u) hits++;
    }
    s_f32 = (hits < 32) ? 1 : 0;
  }

  for (int i = tid; i < 16*1024; i += TPB) ((u16*)ering)[i] = 0;
  for (int i = tid; i < 4*2*512; i += TPB) ((u16*)hbuf)[i]  = 0;
  for (int i = tid; i < 1024;    i += TPB){
    int r = i & 3, s = i >> 2;
    tokl[i] = idx[(r0 + r)*256 + s];
  }
  __syncthreads();
  const bool f32in = (s_f32 != 0);

  // ---- z-GEMM B-frags, GATE-MAJOR cols (R22/R23-verified): lane owns unit
  // jown = wv*16 + (ln&15); tile t = gate t, B col = t*50 + jown.
  const int jown = wv*16 + (ln & 15);
  const bool jval = (jown < 50);
  s16x8 bz[4][4];
  #pragma unroll
  for (int t = 0; t < 4; t++){
    const int col = t*50 + jown;
    #pragma unroll
    for (int kt = 0; kt < 4; kt++){
      s16x8 v;
      #pragma unroll
      for (int j = 0; j < 8; j++){
        int k = kt*32 + ((ln >> 4) << 3) + j;
        float w = 0.f;
        if (jval){
          if (k < 50)                  w = ldf(Uk, k*200 + col, f32in);
          else if (k >= 64 && k < 114) w = ldf(Wk, (k-64)*200 + col, f32in);
        }
        v[j] = (short)f2bf(w);
      }
      bz[t][kt] = v;
    }
  }
  f32x4 bgv[4];                                   // bias splat (C-init for ae)
  #pragma unroll
  for (int t = 0; t < 4; t++){
    float b = jval ? ldf(bias, t*50 + jown, f32in) : 0.f;
    bgv[t] = (f32x4){b, b, b, b};
  }

  // ---- dense W1 fragments + b1/W2 ----
  s16x8 w1f[4][2];
  float b1v[4], w2v[4];
  #pragma unroll
  for (int nt = 0; nt < 4; nt++){
    int c = nt*16 + (ln & 15);
    b1v[nt] = (c < 50) ? ldf(b1, c, f32in) : 0.f;
    w2v[nt] = (c < 50) ? ldf(W2, c, f32in) : 0.f;
    #pragma unroll
    for (int kt = 0; kt < 2; kt++){
      s16x8 v;
      #pragma unroll
      for (int j = 0; j < 8; j++){
        int k = kt*32 + ((ln >> 4) << 3) + j;
        v[j] = (short)((k < 50 && c < 50) ? f2bf(ldf(W1, k*50 + c, f32in)) : (u16)0);
      }
      w1f[nt][kt] = v;
    }
  }
  const float b2s = ldf(b2, 0, f32in);

  const int gr = tid / 50, gj = tid - gr*50;      // gather threads 0..199, gr 0..3
  const int foff = (gj >> 5)*512 + (gr + (((gj & 31) >> 3) << 4))*8 + (gj & 7);

  // ---- gate spread (R28): ONE fan stage, 2 cells/lane.
  //   lo half (q0,q1): rows 0,1 from own acc[0],acc[1]
  //   hi half (q2,q3): rows 2,3 via shfl_xor(32) of partner acc[2],acc[3]
  //   q1/q3 garbage (finite) -> excluded from writes.
  const int q  = ln >> 4;
  const int hi = q >> 1;
  const bool wrt = jval && ((q & 1) == 0);        // one writer per (rowpair,unit)
  float creg[2] = {0.f, 0.f};                     // cell state rows hi*2+{0,1}
  const int eo16 = ((jown & 31) >> 3) << 4;

  auto dense_head = [&](int tcd){
    const int mt = wv;                             // 64 m-rows -> 1 tile/wave
    s16x8 a0 = *(const s16x8*)&hbuf[mt][0][ln*8];
    s16x8 a1 = *(const s16x8*)&hbuf[mt][1][ln*8];
    #pragma unroll
    for (int nt = 0; nt < 4; nt++){                // d1 = relu(h@W1+b1)
      f32x4 acc = {0.f,0.f,0.f,0.f};
      acc = mf(a0, w1f[nt][0], acc);
      acc = mf(a1, w1f[nt][1], acc);
      int c = nt*16 + (ln & 15);
      #pragma unroll
      for (int r = 0; r < 4; r++){
        float v = fmaxf(acc[r] + b1v[nt], 0.f);
        int row16 = ((ln >> 4) << 2) + r;
        dwork[wv][c >> 5][(row16 + (((c & 31) >> 3) << 4))*8 + (c & 7)] = f2bf(v);
      }
    }
    s16x8 d0 = *(const s16x8*)&dwork[wv][0][ln*8];
    s16x8 d1 = *(const s16x8*)&dwork[wv][1][ln*8];
    float part[4] = {0.f,0.f,0.f,0.f};
    #pragma unroll
    for (int nt = 0; nt < 4; nt++){                // d2 = relu(d1@W1+b1) . W2
      f32x4 acc = {0.f,0.f,0.f,0.f};
      acc = mf(d0, w1f[nt][0], acc);
      acc = mf(d1, w1f[nt][1], acc);
      #pragma unroll
      for (int r = 0; r < 4; r++)
        part[r] += fmaxf(acc[r] + b1v[nt], 0.f) * w2v[nt];
    }
    #pragma unroll
    for (int d = 1; d < 16; d <<= 1)
      #pragma unroll
      for (int r = 0; r < 4; r++) part[r] += __shfl_xor(part[r], d, 16);
    if ((ln & 15) == 0){
      int qq = ln >> 4;
      #pragma unroll
      for (int r = 0; r < 4; r++){
        int m = mt*16 + (qq << 2) + r;
        int sl4 = m >> 2, rb = m & 3;
        float z = part[r] + b2s;
        z = fmaxf(fminf(z, 1.0f), -1.0f);          // safety clamp
        out[(r0 + rb)*256 + tcd + sl4] = sigm_f(z);
      }
    }
  };

  // ---- prologue: issue chunk-0 gather loads into registers ----
  float ev[16];
  if (tid < 200){
    #pragma unroll
    for (int sl = 0; sl < 16; sl++)
      ev[sl] = ldf(emb, tokl[sl*4 + gr]*50 + gj, f32in);
  }

  for (int ch = 0; ch < 16; ch++){
    const int tc = ch*16;

    // ---- write ering from regs; issue next chunk's loads; head off-chain ----
    if (tid < 200){
      #pragma unroll
      for (int sl = 0; sl < 16; sl++)
        ering[sl][foff] = f2bf(ev[sl]);
      if (ch < 15){
        const int tn = tc + 16;
        #pragma unroll
        for (int sl = 0; sl < 16; sl++)
          ev[sl] = ldf(emb, tokl[(tn + sl)*4 + gr]*50 + gj, f32in);
      }
    }
    if (ch > 0) dense_head(tc - 16);    // prev chunk's head, off the chain
    WGBAR();                             // ering ready; hbuf consumed (LDS only)

    // ---- sl=0 e-part + bias, folded into C-init (split-K, off-chain) ----
    s16x8 e0 = *(const s16x8*)&ering[0][ln*8];
    s16x8 e1 = *(const s16x8*)&ering[0][512 + ln*8];
    f32x4 ae[4];
    #pragma unroll
    for (int t = 0; t < 4; t++){
      f32x4 a = bgv[t];
      a = mf(e1, bz[t][3], a);
      a = mf(e0, bz[t][2], a);
      ae[t] = a;
    }

    for (int sl = 0; sl < 16; sl++){
      // ---- A-frags straight from hbuf (h written at step sl-1) ----
      const int prev = (sl + 15) & 15;
      const int aoffr = ln*8 + (prev & 3)*32;
      s16x8 av0 = *(const s16x8*)&hbuf[prev >> 2][0][aoffr];
      s16x8 av1 = *(const s16x8*)&hbuf[prev >> 2][1][aoffr];
      f32x4 g4[4];
      #pragma unroll
      for (int t = 0; t < 4; t++){
        f32x4 a = ae[t];                 // C-init carries e-part + bias
        a = mf(av0, bz[t][0], a);
        a = mf(av1, bz[t][1], a);
        g4[t] = a;
      }

      // ---- ONE fan stage: hi half pulls rows 2,3; 2 cells per lane ----
      float z0[4], z1[4];
      #pragma unroll
      for (int t = 0; t < 4; t++){
        float s2 = __shfl_xor(g4[t][2], 32);
        float s3 = __shfl_xor(g4[t][3], 32);
        z0[t] = hi ? s2 : g4[t][0];
        z1[t] = hi ? s3 : g4[t][1];
      }

      // ---- gates in-register, 2 cells/lane (rows hi*2+{0,1}, unit jown) ----
      float iv0 = sigm_f(z0[0]), fv0 = sigm_f(z0[1]);
      float gv0 = tanh_f(z0[2]), ov0 = sigm_f(z0[3]);
      float iv1 = sigm_f(z1[0]), fv1 = sigm_f(z1[1]);
      float gv1 = tanh_f(z1[2]), ov1 = sigm_f(z1[3]);
      float c0 = fv0 * creg[0] + iv0 * gv0;  creg[0] = c0;
      float c1 = fv1 * creg[1] + iv1 * gv1;  creg[1] = c1;
      u16 hb0 = f2bf(ov0 * tanh_f(c0));
      u16 hb1 = f2bf(ov1 * tanh_f(c1));
      if (wrt){
        const int m0 = sl*4 + hi*2;            // row = hi*2 + rp
        hbuf[m0 >> 4][jown >> 5][((m0 & 15) + eo16)*8 + (jown & 7)] = hb0;
        const int m1 = m0 + 1;
        hbuf[m1 >> 4][jown >> 5][((m1 & 15) + eo16)*8 + (jown & 7)] = hb1;
      }

      // ---- pre-barrier: next step's e-frags + e-part MFMAs (off-chain) ----
      if (sl < 15){
        e0 = *(const s16x8*)&ering[sl + 1][ln*8];
        e1 = *(const s16x8*)&ering[sl + 1][512 + ln*8];
        #pragma unroll
        for (int t = 0; t < 4; t++){
          f32x4 a = bgv[t];
          a = mf(e1, bz[t][3], a);
          a = mf(e0, bz[t][2], a);
          ae[t] = a;
        }
      }
      WGBAR();           // h visible -> next step may read (LDS only)
    }
  }

  dense_head(240);                       // last chunk's head
}

extern "C" void kernel_launch(void* const* d_in, const int* in_sizes, int n_in,
                              void* d_out, int out_size, void* d_ws, size_t ws_size,
                              hipStream_t stream) {
  (void)in_sizes; (void)n_in; (void)out_size; (void)d_ws; (void)ws_size;
  hipLaunchKernelGGL(LSTM_Seq2Dis_15272903704706_kernel,
                     dim3(512), dim3(TPB), 0, stream,
                     (const int*)d_in[0], d_in[1], d_in[2], d_in[3], d_in[4],
                     d_in[5], d_in[6], d_in[7], d_in[8], (float*)d_out);
}